// Round 8
// baseline (26.265 us; speedup 1.0000x reference)
//
#include <hip/hip_runtime.h>
#include <math.h>

constexpr int Bn = 1024, Tn = 6, Vn = 100, Pn = 20, Cn = 3;
constexpr int NT = 512;                 // 8 waves per block
constexpr int NBLK = 512;               // block i handles b=i and b=i+NBLK
constexpr int NF4 = Vn * Pn * 2 / 4;    // 1000 float4 per batch element
constexpr unsigned TAG = 0x13579BDFu;

__global__ __launch_bounds__(NT, 4) void pmbl_fused(
    const float* __restrict__ ego,            // (B, T, 2)
    const float* __restrict__ lane,           // (B, V, P, 2)
    const float* __restrict__ score,          // (B, V, C)
    float* __restrict__ out,                  // scalar
    unsigned long long* __restrict__ slots)   // (B) {TAG, f32 bits} per b
{
    const int tid = threadIdx.x;
    const int bA = blockIdx.x;
    const int bB = bA + NBLK;

    __shared__ int smA[Vn], smB[Vn];          // 1 = not-a-bound (masked)
    __shared__ unsigned long long red[NT / 64][Tn];
    __shared__ int imA, imB;
    __shared__ double sm[NT / 64];

    // --- issue ALL heavy loads for BOTH b's up front: one latency window ---
    const float4* lpA = reinterpret_cast<const float4*>(
        lane + (size_t)bA * (Vn * Pn * 2));
    const float4* lpB = reinterpret_cast<const float4*>(
        lane + (size_t)bB * (Vn * Pn * 2));
    const bool has1 = tid < NF4 - NT;         // tid < 488
    float4 qA0 = lpA[tid];
    float4 qA1 = has1 ? lpA[tid + NT] : make_float4(0.f, 0.f, 0.f, 0.f);
    float4 qB0 = lpB[tid];
    float4 qB1 = has1 ? lpB[tid + NT] : make_float4(0.f, 0.f, 0.f, 0.f);

    if (tid < Vn) {
        smA[tid] = (score[(size_t)bA * (Vn * Cn) + tid * Cn + 2] < 0.5f) ? 1 : 0;
        smB[tid] = (score[(size_t)bB * (Vn * Cn) + tid * Cn + 2] < 0.5f) ? 1 : 0;
    }
    if (tid == 0) { imA = 0; imB = 0; }
    __syncthreads();

    // process one batch element end-to-end (phase1 + reduce + phase2 + publish)
    auto run = [&](int b, const float4* lp4, float4 q0, float4 q1,
                   const int* smask, int* im) {
        // ego cumsum (uniform loads; L2/L3-hot after first replay)
        float px[Tn], py[Tn], sx[Tn], sy[Tn];
        {
            const float* e = ego + (size_t)b * (Tn * 2);
            float cx = 0.f, cy = 0.f;
            #pragma unroll
            for (int t = 0; t < Tn; ++t) {
                sx[t] = cx; sy[t] = cy;
                cx += e[2 * t];
                cy += e[2 * t + 1];
                px[t] = cx; py[t] = cy;
            }
        }

        // phase 1: per-thread (min sq dist, first flat idx) per t
        float best[Tn]; int bidx[Tn];
        #pragma unroll
        for (int t = 0; t < Tn; ++t) { best[t] = __builtin_inff(); bidx[t] = 0; }

        auto process = [&](int f, float4 q) {
            const int v = f / 10;             // 10 float4 per lane
            const bool nb = smask[v] != 0;
            const float x0 = nb ? 1e6f : fmaf(q.x, 30.f, -15.f);
            const float y0 = nb ? 1e6f : fmaf(q.y, 60.f, -30.f);
            const float x1 = nb ? 1e6f : fmaf(q.z, 30.f, -15.f);
            const float y1 = nb ? 1e6f : fmaf(q.w, 60.f, -30.f);
            const int p0 = 2 * f, p1 = 2 * f + 1;
            #pragma unroll
            for (int t = 0; t < Tn; ++t) {
                float dx0 = px[t] - x0, dy0 = py[t] - y0;
                float s0 = fmaf(dx0, dx0, dy0 * dy0);
                float dx1 = px[t] - x1, dy1 = py[t] - y1;
                float s1 = fmaf(dx1, dx1, dy1 * dy1);
                if (s0 < best[t]) { best[t] = s0; bidx[t] = p0; }
                if (s1 < best[t]) { best[t] = s1; bidx[t] = p1; }
            }
        };
        process(tid, q0);
        if (has1) process(tid + NT, q1);

        // u64 pack: (val_bits<<32)|flat_idx -> min == first-occurrence argmin
        unsigned long long pk[Tn];
        #pragma unroll
        for (int t = 0; t < Tn; ++t)
            pk[t] = (((unsigned long long)__float_as_uint(best[t])) << 32)
                    | (unsigned)bidx[t];
        #pragma unroll
        for (int off = 32; off > 0; off >>= 1) {
            #pragma unroll
            for (int t = 0; t < Tn; ++t) {
                unsigned long long o = __shfl_xor(pk[t], off);
                pk[t] = (o < pk[t]) ? o : pk[t];
            }
        }
        if ((tid & 63) == 0) {
            #pragma unroll
            for (int t = 0; t < Tn; ++t) red[tid >> 6][t] = pk[t];
        }
        __syncthreads();

        unsigned long long comb[Tn];
        #pragma unroll
        for (int t = 0; t < Tn; ++t) {
            unsigned long long m = red[0][t];
            #pragma unroll
            for (int w = 1; w < NT / 64; ++w) {
                unsigned long long c = red[w][t];
                m = (c < m) ? c : m;
            }
            comb[t] = m;
        }

        // phase 2: 114 segment-intersection tests (winning lane is L1-hot)
        if (tid < Tn * (Pn - 1)) {
            const int t = tid / (Pn - 1);
            const int s = tid % (Pn - 1);
            const int vt = (int)(comb[t] & 0xffffffffu) / Pn;
            const bool nb = smask[vt] != 0;
            const float* lp = reinterpret_cast<const float*>(lp4) + vt * (Pn * 2);
            float ax = nb ? 1e6f : fmaf(lp[2 * s + 0], 30.f, -15.f);
            float ay = nb ? 1e6f : fmaf(lp[2 * s + 1], 60.f, -30.f);
            float bx = nb ? 1e6f : fmaf(lp[2 * s + 2], 30.f, -15.f);
            float by = nb ? 1e6f : fmaf(lp[2 * s + 3], 60.f, -30.f);
            float d1x = px[t] - sx[t], d1y = py[t] - sy[t];
            float d2x = bx - ax, d2y = by - ay;
            float det = d1x * d2y - d1y * d2x;
            if (det != 0.f) {
                float dx = ax - sx[t], dy = ay - sy[t];
                float tt = (dx * d2y - dy * d2x) / det;
                float uu = (dx * d1y - dy * d1x) / det;
                if (tt >= 0.f && tt <= 1.f && uu >= 0.f && uu <= 1.f)
                    atomicOr(im, 1 << t);
            }
        }
        __syncthreads();

        // publish {TAG, sum}; other threads may proceed (no LDS use below)
        if (tid == 0) {
            const int m = *im;
            int first_t = Tn;
            #pragma unroll
            for (int t = Tn - 1; t >= 0; --t)
                if ((m >> t) & 1) first_t = t;
            float sum = 0.f;
            for (int t = 0; t < first_t; ++t) {
                float d = sqrtf(__uint_as_float((unsigned)(comb[t] >> 32)));
                sum += (d > 1.f) ? 0.f : (1.f - d);
            }
            unsigned long long v = (((unsigned long long)TAG) << 32)
                                 | (unsigned long long)__float_as_uint(sum);
            __hip_atomic_store(&slots[b], v, __ATOMIC_RELAXED,
                               __HIP_MEMORY_SCOPE_AGENT);
        }
    };

    run(bA, lpA, qA0, qA1, smA, &imA);
    run(bB, lpB, qB0, qB1, smB, &imB);

    // block 0 gathers all slots (tag carries validity; values deterministic)
    if (blockIdx.x == 0) {
        double s = 0.0;
        #pragma unroll
        for (int r = 0; r < Bn / NT; ++r) {
            const int j = tid + r * NT;
            unsigned long long v = __hip_atomic_load(
                &slots[j], __ATOMIC_RELAXED, __HIP_MEMORY_SCOPE_AGENT);
            while ((unsigned)(v >> 32) != TAG) {
                __builtin_amdgcn_s_sleep(1);
                v = __hip_atomic_load(&slots[j], __ATOMIC_RELAXED,
                                      __HIP_MEMORY_SCOPE_AGENT);
            }
            s += (double)__uint_as_float((unsigned)(v & 0xffffffffu));
        }
        #pragma unroll
        for (int off = 32; off > 0; off >>= 1) s += __shfl_xor(s, off);
        if ((tid & 63) == 0) sm[tid >> 6] = s;
        __syncthreads();
        if (tid == 0) {
            double tot = 0.0;
            #pragma unroll
            for (int w = 0; w < NT / 64; ++w) tot += sm[w];
            out[0] = (float)(tot / (double)(Bn * Tn));
        }
    }
}

extern "C" void kernel_launch(void* const* d_in, const int* in_sizes, int n_in,
                              void* d_out, int out_size, void* d_ws, size_t ws_size,
                              hipStream_t stream) {
    const float* ego   = (const float*)d_in[0];
    const float* lane  = (const float*)d_in[1];
    const float* score = (const float*)d_in[2];
    float* out = (float*)d_out;
    unsigned long long* slots = (unsigned long long*)d_ws;

    pmbl_fused<<<NBLK, NT, 0, stream>>>(ego, lane, score, out, slots);
}

// Round 9
// 21.801 us; speedup vs baseline: 1.2048x; 1.2048x over previous
//
#include <hip/hip_runtime.h>
#include <math.h>

constexpr int Bn = 1024, Tn = 6, Vn = 100, Pn = 20, Cn = 3;
constexpr int NT = 512;                 // 8 waves, one b per block -> 32 waves/CU
constexpr int NF4 = Vn * Pn * 2 / 4;    // 1000 float4 per batch element
constexpr unsigned TAG = 0x13579BDFu;

__global__ __launch_bounds__(NT, 4) void pmbl_fused(
    const float* __restrict__ ego,            // (B, T, 2)
    const float* __restrict__ lane,           // (B, V, P, 2)
    const float* __restrict__ score,          // (B, V, C)
    float* __restrict__ out,                  // scalar
    unsigned long long* __restrict__ slots)   // (B) {TAG, f32 bits} per b
{
    const int b = blockIdx.x;
    const int tid = threadIdx.x;

    __shared__ int smask[Vn];                 // 1 = not-a-bound (masked)
    __shared__ unsigned long long red[NT / 64][Tn];
    __shared__ int interMask;
    __shared__ double sm[NT / 64];

    // --- issue all global loads up front: one latency window ---
    const float4* lp4 = reinterpret_cast<const float4*>(
        lane + (size_t)b * (Vn * Pn * 2));
    float4 q0 = lp4[tid];
    const bool has1 = tid < NF4 - NT;         // tid < 488
    float4 q1 = has1 ? lp4[tid + NT] : make_float4(0.f, 0.f, 0.f, 0.f);

    float scv = 0.f;
    if (tid < Vn) scv = score[(size_t)b * (Vn * Cn) + tid * Cn + 2];

    // ego cumsum (uniform scalar loads)
    float px[Tn], py[Tn], sx[Tn], sy[Tn];
    {
        const float* e = ego + (size_t)b * (Tn * 2);
        float cx = 0.f, cy = 0.f;
        #pragma unroll
        for (int t = 0; t < Tn; ++t) {
            sx[t] = cx; sy[t] = cy;
            cx += e[2 * t];
            cy += e[2 * t + 1];
            px[t] = cx; py[t] = cy;
        }
    }

    if (tid < Vn) smask[tid] = (scv < 0.5f) ? 1 : 0;
    if (tid == 0) interMask = 0;
    __syncthreads();

    // phase 1: per-thread (min sq dist, first flat idx) per t — 2 float4/thread
    float best[Tn]; int bidx[Tn];
    #pragma unroll
    for (int t = 0; t < Tn; ++t) { best[t] = __builtin_inff(); bidx[t] = 0; }

    auto process = [&](int f, float4 q) {
        const int v = f / 10;                 // 10 float4 per lane
        const bool nb = smask[v] != 0;
        const float x0 = nb ? 1e6f : fmaf(q.x, 30.f, -15.f);
        const float y0 = nb ? 1e6f : fmaf(q.y, 60.f, -30.f);
        const float x1 = nb ? 1e6f : fmaf(q.z, 30.f, -15.f);
        const float y1 = nb ? 1e6f : fmaf(q.w, 60.f, -30.f);
        const int p0 = 2 * f, p1 = 2 * f + 1;
        #pragma unroll
        for (int t = 0; t < Tn; ++t) {
            float dx0 = px[t] - x0, dy0 = py[t] - y0;
            float s0 = fmaf(dx0, dx0, dy0 * dy0);
            float dx1 = px[t] - x1, dy1 = py[t] - y1;
            float s1 = fmaf(dx1, dx1, dy1 * dy1);
            if (s0 < best[t]) { best[t] = s0; bidx[t] = p0; }
            if (s1 < best[t]) { best[t] = s1; bidx[t] = p1; }
        }
    };
    process(tid, q0);
    if (has1) process(tid + NT, q1);

    // u64 pack: (val_bits<<32)|flat_idx -> min == first-occurrence argmin
    unsigned long long pk[Tn];
    #pragma unroll
    for (int t = 0; t < Tn; ++t)
        pk[t] = (((unsigned long long)__float_as_uint(best[t])) << 32)
                | (unsigned)bidx[t];
    #pragma unroll
    for (int off = 32; off > 0; off >>= 1) {
        #pragma unroll
        for (int t = 0; t < Tn; ++t) {
            unsigned long long o = __shfl_xor(pk[t], off);
            pk[t] = (o < pk[t]) ? o : pk[t];
        }
    }
    if ((tid & 63) == 0) {
        #pragma unroll
        for (int t = 0; t < Tn; ++t) red[tid >> 6][t] = pk[t];
    }
    __syncthreads();

    unsigned long long comb[Tn];
    #pragma unroll
    for (int t = 0; t < Tn; ++t) {
        unsigned long long m = red[0][t];
        #pragma unroll
        for (int w = 1; w < NT / 64; ++w) {
            unsigned long long c = red[w][t];
            m = (c < m) ? c : m;
        }
        comb[t] = m;
    }

    // phase 2: 114 segment-intersection tests (winning lane is L1-hot)
    if (tid < Tn * (Pn - 1)) {
        const int t = tid / (Pn - 1);
        const int s = tid % (Pn - 1);
        const int vt = (int)(comb[t] & 0xffffffffu) / Pn;
        const bool nb = smask[vt] != 0;
        const float* lp = reinterpret_cast<const float*>(lp4) + vt * (Pn * 2);
        float ax = nb ? 1e6f : fmaf(lp[2 * s + 0], 30.f, -15.f);
        float ay = nb ? 1e6f : fmaf(lp[2 * s + 1], 60.f, -30.f);
        float bx = nb ? 1e6f : fmaf(lp[2 * s + 2], 30.f, -15.f);
        float by = nb ? 1e6f : fmaf(lp[2 * s + 3], 60.f, -30.f);
        float d1x = px[t] - sx[t], d1y = py[t] - sy[t];
        float d2x = bx - ax, d2y = by - ay;
        float det = d1x * d2y - d1y * d2x;
        if (det != 0.f) {
            float dx = ax - sx[t], dy = ay - sy[t];
            float tt = (dx * d2y - dy * d2x) / det;
            float uu = (dx * d1y - dy * d1x) / det;
            if (tt >= 0.f && tt <= 1.f && uu >= 0.f && uu <= 1.f)
                atomicOr(&interMask, 1 << t);
        }
    }
    __syncthreads();

    // tail: publish {TAG, sum} as one relaxed 64-bit device-scope atomic
    if (tid == 0) {
        const int im = interMask;
        int first_t = Tn;
        #pragma unroll
        for (int t = Tn - 1; t >= 0; --t)
            if ((im >> t) & 1) first_t = t;
        float sum = 0.f;
        for (int t = 0; t < first_t; ++t) {
            float d = sqrtf(__uint_as_float((unsigned)(comb[t] >> 32)));
            sum += (d > 1.f) ? 0.f : (1.f - d);
        }
        unsigned long long v = (((unsigned long long)TAG) << 32)
                             | (unsigned long long)__float_as_uint(sum);
        __hip_atomic_store(&slots[b], v, __ATOMIC_RELAXED,
                           __HIP_MEMORY_SCOPE_AGENT);
    }

    // block 0 gathers all slots: 2 per thread, round-robin (parallel) polling
    if (b == 0) {
        unsigned long long v0, v1;
        bool d0 = false, d1 = false;
        const int j0 = tid, j1 = tid + NT;
        do {
            if (!d0) {
                v0 = __hip_atomic_load(&slots[j0], __ATOMIC_RELAXED,
                                       __HIP_MEMORY_SCOPE_AGENT);
                d0 = ((unsigned)(v0 >> 32) == TAG);
            }
            if (!d1) {
                v1 = __hip_atomic_load(&slots[j1], __ATOMIC_RELAXED,
                                       __HIP_MEMORY_SCOPE_AGENT);
                d1 = ((unsigned)(v1 >> 32) == TAG);
            }
            if (!(d0 && d1)) __builtin_amdgcn_s_sleep(1);
        } while (!(d0 && d1));

        double s = (double)__uint_as_float((unsigned)(v0 & 0xffffffffu))
                 + (double)__uint_as_float((unsigned)(v1 & 0xffffffffu));
        #pragma unroll
        for (int off = 32; off > 0; off >>= 1) s += __shfl_xor(s, off);
        if ((tid & 63) == 0) sm[tid >> 6] = s;
        __syncthreads();
        if (tid == 0) {
            double tot = 0.0;
            #pragma unroll
            for (int w = 0; w < NT / 64; ++w) tot += sm[w];
            out[0] = (float)(tot / (double)(Bn * Tn));
        }
    }
}

extern "C" void kernel_launch(void* const* d_in, const int* in_sizes, int n_in,
                              void* d_out, int out_size, void* d_ws, size_t ws_size,
                              hipStream_t stream) {
    const float* ego   = (const float*)d_in[0];
    const float* lane  = (const float*)d_in[1];
    const float* score = (const float*)d_in[2];
    float* out = (float*)d_out;
    unsigned long long* slots = (unsigned long long*)d_ws;

    pmbl_fused<<<Bn, NT, 0, stream>>>(ego, lane, score, out, slots);
}

// Round 10
// 19.737 us; speedup vs baseline: 1.3307x; 1.1046x over previous
//
#include <hip/hip_runtime.h>
#include <math.h>

constexpr int Bn = 1024, Tn = 6, Vn = 100, Pn = 20, Cn = 3;
constexpr int NF4 = Vn * Pn * 2 / 4;    // 1000 float4 per batch element
constexpr int K = 16;                   // float4 chunks per lane (16*64 >= 1000)
constexpr unsigned TAG = 0x13579BDFu;

// one 64-lane wave per batch element: no barriers, no LDS
__global__ __launch_bounds__(64, 1) void pmbl_wave(
    const float* __restrict__ ego,            // (B, T, 2)
    const float* __restrict__ lane,           // (B, V, P, 2)
    const float* __restrict__ score,          // (B, V, C)
    float* __restrict__ out,                  // scalar
    unsigned long long* __restrict__ slots)   // (B) {TAG, f32 bits} per b
{
    const int b = blockIdx.x;
    const int ln = threadIdx.x;               // 0..63

    const float4* lp4 = reinterpret_cast<const float4*>(
        lane + (size_t)b * (Vn * Pn * 2));
    const float* scb = score + (size_t)b * (Vn * Cn);

    // --- stage ALL loads up front: one latency window, coalesced f = k*64+ln ---
    float4 q[K]; float sc[K];
    #pragma unroll
    for (int k = 0; k < K; ++k) {
        const int f = k * 64 + ln;
        const bool ok = f < NF4;
        q[k]  = ok ? lp4[f] : make_float4(0.f, 0.f, 0.f, 0.f);
        sc[k] = ok ? scb[(f / 10) * Cn + 2] : 0.f;   // ~7 lines/wave, broadcast
    }

    float px[Tn], py[Tn], sx[Tn], sy[Tn];
    {
        const float* e = ego + (size_t)b * (Tn * 2);
        float cx = 0.f, cy = 0.f;
        #pragma unroll
        for (int t = 0; t < Tn; ++t) {
            sx[t] = cx; sy[t] = cy;
            cx += e[2 * t];
            cy += e[2 * t + 1];
            px[t] = cx; py[t] = cy;
        }
    }

    // phase 1: per-lane (min sq dist, first flat idx) per t
    float best[Tn]; int bidx[Tn];
    #pragma unroll
    for (int t = 0; t < Tn; ++t) { best[t] = __builtin_inff(); bidx[t] = 0; }

    #pragma unroll
    for (int k = 0; k < K; ++k) {
        const int f = k * 64 + ln;
        if (f < NF4) {
            const bool nb = sc[k] < 0.5f;     // not-a-bound -> masked to 1e6
            const float x0 = nb ? 1e6f : fmaf(q[k].x, 30.f, -15.f);
            const float y0 = nb ? 1e6f : fmaf(q[k].y, 60.f, -30.f);
            const float x1 = nb ? 1e6f : fmaf(q[k].z, 30.f, -15.f);
            const float y1 = nb ? 1e6f : fmaf(q[k].w, 60.f, -30.f);
            const int p0 = 2 * f, p1 = 2 * f + 1;
            #pragma unroll
            for (int t = 0; t < Tn; ++t) {
                float dx0 = px[t] - x0, dy0 = py[t] - y0;
                float s0 = fmaf(dx0, dx0, dy0 * dy0);
                float dx1 = px[t] - x1, dy1 = py[t] - y1;
                float s1 = fmaf(dx1, dx1, dy1 * dy1);
                if (s0 < best[t]) { best[t] = s0; bidx[t] = p0; }
                if (s1 < best[t]) { best[t] = s1; bidx[t] = p1; }
            }
        }
    }

    // u64 pack (val_bits<<32)|flat_idx; 64-lane xor-butterfly min:
    // every lane ends with (min value, first-occurrence flat idx) == jnp tie-break
    unsigned long long pk[Tn];
    #pragma unroll
    for (int t = 0; t < Tn; ++t)
        pk[t] = (((unsigned long long)__float_as_uint(best[t])) << 32)
                | (unsigned)bidx[t];
    #pragma unroll
    for (int off = 32; off > 0; off >>= 1) {
        #pragma unroll
        for (int t = 0; t < Tn; ++t) {
            unsigned long long o = __shfl_xor(pk[t], off);
            pk[t] = (o < pk[t]) ? o : pk[t];
        }
    }

    // phase 2: 114 intersection tests in 2 rounds; OR-butterfly the t-mask
    unsigned im = 0;
    #pragma unroll
    for (int r = 0; r < 2; ++r) {
        const int i = r * 64 + ln;
        if (i < Tn * (Pn - 1)) {
            const int t = i / (Pn - 1);
            const int s = i % (Pn - 1);
            const unsigned idx = (unsigned)(pk[t] & 0xffffffffu);
            const int vt = (int)(idx / (unsigned)Pn);
            const bool nb = scb[vt * Cn + 2] < 0.5f;
            const float* lp = reinterpret_cast<const float*>(lp4) + vt * (Pn * 2);
            float ax = nb ? 1e6f : fmaf(lp[2 * s + 0], 30.f, -15.f);
            float ay = nb ? 1e6f : fmaf(lp[2 * s + 1], 60.f, -30.f);
            float bx = nb ? 1e6f : fmaf(lp[2 * s + 2], 30.f, -15.f);
            float by = nb ? 1e6f : fmaf(lp[2 * s + 3], 60.f, -30.f);
            float d1x = px[t] - sx[t], d1y = py[t] - sy[t];
            float d2x = bx - ax, d2y = by - ay;
            float det = d1x * d2y - d1y * d2x;
            if (det != 0.f) {
                float dx = ax - sx[t], dy = ay - sy[t];
                float tt = (dx * d2y - dy * d2x) / det;
                float uu = (dx * d1y - dy * d1x) / det;
                if (tt >= 0.f && tt <= 1.f && uu >= 0.f && uu <= 1.f)
                    im |= (1u << t);
            }
        }
    }
    #pragma unroll
    for (int off = 32; off > 0; off >>= 1) im |= __shfl_xor(im, off);

    // lane 0: tail sum + publish {TAG, sum}
    if (ln == 0) {
        int first_t = Tn;
        #pragma unroll
        for (int t = Tn - 1; t >= 0; --t)
            if ((im >> t) & 1) first_t = t;
        float sum = 0.f;
        for (int t = 0; t < first_t; ++t) {
            float d = sqrtf(__uint_as_float((unsigned)(pk[t] >> 32)));
            sum += (d > 1.f) ? 0.f : (1.f - d);
        }
        unsigned long long v = (((unsigned long long)TAG) << 32)
                             | (unsigned long long)__float_as_uint(sum);
        __hip_atomic_store(&slots[b], v, __ATOMIC_RELAXED,
                           __HIP_MEMORY_SCOPE_AGENT);
    }

    // block 0's wave gathers all 1024 slots (16 per lane, fixed order)
    if (b == 0) {
        double s = 0.0;
        #pragma unroll
        for (int r = 0; r < Bn / 64; ++r) {
            const int j = r * 64 + ln;
            unsigned long long v = __hip_atomic_load(
                &slots[j], __ATOMIC_RELAXED, __HIP_MEMORY_SCOPE_AGENT);
            while ((unsigned)(v >> 32) != TAG) {
                __builtin_amdgcn_s_sleep(1);
                v = __hip_atomic_load(&slots[j], __ATOMIC_RELAXED,
                                      __HIP_MEMORY_SCOPE_AGENT);
            }
            s += (double)__uint_as_float((unsigned)(v & 0xffffffffu));
        }
        #pragma unroll
        for (int off = 32; off > 0; off >>= 1) s += __shfl_xor(s, off);
        if (ln == 0)
            out[0] = (float)(s / (double)(Bn * Tn));
    }
}

extern "C" void kernel_launch(void* const* d_in, const int* in_sizes, int n_in,
                              void* d_out, int out_size, void* d_ws, size_t ws_size,
                              hipStream_t stream) {
    const float* ego   = (const float*)d_in[0];
    const float* lane  = (const float*)d_in[1];
    const float* score = (const float*)d_in[2];
    float* out = (float*)d_out;
    unsigned long long* slots = (unsigned long long*)d_ws;

    pmbl_wave<<<Bn, 64, 0, stream>>>(ego, lane, score, out, slots);
}

// Round 11
// 14.118 us; speedup vs baseline: 1.8604x; 1.3980x over previous
//
#include <hip/hip_runtime.h>
#include <math.h>

constexpr int Bn = 1024, Tn = 6, Vn = 100, Pn = 20, Cn = 3;
constexpr int NT = 256;                       // threads per block (4 waves)
constexpr int NF4 = Vn * Pn * 2 / 4;          // 1000 float4 per batch element
constexpr unsigned TAG = 0x13579BDFu;
constexpr unsigned IDX_NONE = 0xffffffffu;

// deterministic op sequence (explicit fmaf) so phase-1 and rescan agree bit-exact
__device__ __forceinline__ float sqd(float px, float py, float x, float y) {
    float dx = px - x, dy = py - y;
    return fmaf(dx, dx, dy * dy);
}

__device__ __forceinline__ void coords(float4 q, bool nb,
                                       float& x0, float& y0,
                                       float& x1, float& y1) {
    x0 = nb ? 1e6f : fmaf(q.x, 30.f, -15.f);
    y0 = nb ? 1e6f : fmaf(q.y, 60.f, -30.f);
    x1 = nb ? 1e6f : fmaf(q.z, 30.f, -15.f);
    y1 = nb ? 1e6f : fmaf(q.w, 60.f, -30.f);
}

__global__ __launch_bounds__(NT) void pmbl_fused(
    const float* __restrict__ ego,            // (B, T, 2)
    const float* __restrict__ lane,           // (B, V, P, 2)
    const float* __restrict__ score,          // (B, V, C)
    float* __restrict__ out,                  // scalar
    unsigned long long* __restrict__ slots)   // (B) {TAG, f32 bits} per b
{
    const int b = blockIdx.x;
    const int tid = threadIdx.x;

    __shared__ int smask[Vn];                 // 1 = not-a-bound (masked)
    __shared__ float redf[NT / 64][Tn];
    __shared__ float Mt[Tn];                  // block-min squared dist per t
    __shared__ unsigned idxMin[Tn];           // smallest achieving flat idx
    __shared__ int interMask;
    __shared__ double sm[NT / 64];

    // --- issue all global loads up front (scv first: the barrier waits on it) ---
    float scv = 0.f;
    if (tid < Vn) scv = score[(size_t)b * (Vn * Cn) + tid * Cn + 2];

    const float4* lp4 = reinterpret_cast<const float4*>(
        lane + (size_t)b * (Vn * Pn * 2));
    float4 q0 = lp4[tid];
    float4 q1 = lp4[tid + NT];
    float4 q2 = lp4[tid + 2 * NT];
    const bool has3 = tid < NF4 - 3 * NT;     // tid < 232
    float4 q3 = has3 ? lp4[tid + 3 * NT] : make_float4(0.f, 0.f, 0.f, 0.f);

    // ego cumsum (uniform scalar loads)
    float px[Tn], py[Tn], sx[Tn], sy[Tn];
    {
        const float* e = ego + (size_t)b * (Tn * 2);
        float cx = 0.f, cy = 0.f;
        #pragma unroll
        for (int t = 0; t < Tn; ++t) {
            sx[t] = cx; sy[t] = cy;
            cx += e[2 * t];
            cy += e[2 * t + 1];
            px[t] = cx; py[t] = cy;
        }
    }

    if (tid < Vn) smask[tid] = (scv < 0.5f) ? 1 : 0;
    if (tid < Tn) idxMin[tid] = IDX_NONE;
    if (tid == 0) interMask = 0;
    __syncthreads();

    // phase 1: value-only min via min3 (no idx tracking in hot loop)
    float best[Tn];
    #pragma unroll
    for (int t = 0; t < Tn; ++t) best[t] = __builtin_inff();

    auto process = [&](int f, float4 q) {
        const int v = f / 10;                 // 10 float4 per lane
        const bool nb = smask[v] != 0;
        float x0, y0, x1, y1;
        coords(q, nb, x0, y0, x1, y1);
        #pragma unroll
        for (int t = 0; t < Tn; ++t) {
            float s0 = sqd(px[t], py[t], x0, y0);
            float s1 = sqd(px[t], py[t], x1, y1);
            best[t] = fminf(best[t], fminf(s0, s1));   // -> v_min3_f32
        }
    };

    process(tid, q0);
    process(tid + NT, q1);
    process(tid + 2 * NT, q2);
    if (has3) process(tid + 3 * NT, q3);

    // f32 butterfly on a copy (keep `best` for the equality rescan)
    float w[Tn];
    #pragma unroll
    for (int t = 0; t < Tn; ++t) w[t] = best[t];
    #pragma unroll
    for (int off = 32; off > 0; off >>= 1) {
        #pragma unroll
        for (int t = 0; t < Tn; ++t)
            w[t] = fminf(w[t], __shfl_xor(w[t], off));
    }
    if ((tid & 63) == 0) {
        #pragma unroll
        for (int t = 0; t < Tn; ++t) redf[tid >> 6][t] = w[t];
    }
    __syncthreads();

    if (tid < Tn) {
        float m = redf[0][tid];
        #pragma unroll
        for (int wv = 1; wv < NT / 64; ++wv) m = fminf(m, redf[wv][tid]);
        Mt[tid] = m;
    }
    __syncthreads();

    // exact argmin recovery: achievers rescan their register-resident candidates;
    // atomicMin over bit-exact matches == smallest flat idx == jnp tie-break
    auto rescan4 = [&](int f, float4 q, float ptx, float pty, float tgt,
                       unsigned* slot) {
        const int v = f / 10;
        const bool nb = smask[v] != 0;
        float x0, y0, x1, y1;
        coords(q, nb, x0, y0, x1, y1);
        if (sqd(ptx, pty, x0, y0) == tgt) atomicMin(slot, 2u * f);
        if (sqd(ptx, pty, x1, y1) == tgt) atomicMin(slot, 2u * f + 1u);
    };
    #pragma unroll
    for (int t = 0; t < Tn; ++t) {
        if (best[t] == Mt[t]) {
            rescan4(tid,          q0, px[t], py[t], Mt[t], &idxMin[t]);
            rescan4(tid + NT,     q1, px[t], py[t], Mt[t], &idxMin[t]);
            rescan4(tid + 2 * NT, q2, px[t], py[t], Mt[t], &idxMin[t]);
            if (has3)
                rescan4(tid + 3 * NT, q3, px[t], py[t], Mt[t], &idxMin[t]);
        }
    }
    __syncthreads();

    // phase 2: 6*19 = 114 segment-intersection tests, one per thread
    if (tid < Tn * (Pn - 1)) {
        const int t = tid / (Pn - 1);
        const int s = tid % (Pn - 1);
        unsigned idx = idxMin[t];
        unsigned vtu = idx / (unsigned)Pn;
        const int vt = (vtu < (unsigned)Vn) ? (int)vtu : 0;  // safety clamp
        const bool nb = smask[vt] != 0;
        const float* lp = lane + ((size_t)b * Vn + vt) * (Pn * 2);
        float ax = nb ? 1e6f : fmaf(lp[2 * s + 0], 30.f, -15.f);
        float ay = nb ? 1e6f : fmaf(lp[2 * s + 1], 60.f, -30.f);
        float bx = nb ? 1e6f : fmaf(lp[2 * s + 2], 30.f, -15.f);
        float by = nb ? 1e6f : fmaf(lp[2 * s + 3], 60.f, -30.f);
        float d1x = px[t] - sx[t], d1y = py[t] - sy[t];
        float d2x = bx - ax, d2y = by - ay;
        float det = d1x * d2y - d1y * d2x;
        if (det != 0.f) {
            float dx = ax - sx[t], dy = ay - sy[t];
            float tt = (dx * d2y - dy * d2x) / det;
            float uu = (dx * d1y - dy * d1x) / det;
            if (tt >= 0.f && tt <= 1.f && uu >= 0.f && uu <= 1.f)
                atomicOr(&interMask, 1 << t);
        }
    }
    __syncthreads();

    // tail: publish {TAG, sum} as one relaxed 64-bit device-scope atomic
    if (tid == 0) {
        const int im = interMask;
        int first_t = Tn;
        #pragma unroll
        for (int t = Tn - 1; t >= 0; --t)
            if ((im >> t) & 1) first_t = t;
        float sum = 0.f;
        for (int t = 0; t < first_t; ++t) {
            float d = sqrtf(Mt[t]);
            sum += (d > 1.f) ? 0.f : (1.f - d);
        }
        unsigned long long v = (((unsigned long long)TAG) << 32)
                             | (unsigned long long)__float_as_uint(sum);
        __hip_atomic_store(&slots[b], v, __ATOMIC_RELAXED,
                           __HIP_MEMORY_SCOPE_AGENT);
    }

    // block 0 gathers all slots (tag carries validity; values deterministic)
    if (b == 0) {
        double s = 0.0;
        for (int j = tid; j < Bn; j += NT) {
            unsigned long long v = __hip_atomic_load(
                &slots[j], __ATOMIC_RELAXED, __HIP_MEMORY_SCOPE_AGENT);
            while ((unsigned)(v >> 32) != TAG) {
                __builtin_amdgcn_s_sleep(8);
                v = __hip_atomic_load(&slots[j], __ATOMIC_RELAXED,
                                      __HIP_MEMORY_SCOPE_AGENT);
            }
            s += (double)__uint_as_float((unsigned)(v & 0xffffffffu));
        }
        #pragma unroll
        for (int off = 32; off > 0; off >>= 1) s += __shfl_xor(s, off);
        if ((tid & 63) == 0) sm[tid >> 6] = s;
        __syncthreads();
        if (tid == 0) {
            double tot = 0.0;
            #pragma unroll
            for (int wv = 0; wv < NT / 64; ++wv) tot += sm[wv];
            out[0] = (float)(tot / (double)(Bn * Tn));
        }
    }
}

extern "C" void kernel_launch(void* const* d_in, const int* in_sizes, int n_in,
                              void* d_out, int out_size, void* d_ws, size_t ws_size,
                              hipStream_t stream) {
    const float* ego   = (const float*)d_in[0];
    const float* lane  = (const float*)d_in[1];
    const float* score = (const float*)d_in[2];
    float* out = (float*)d_out;
    unsigned long long* slots = (unsigned long long*)d_ws;

    pmbl_fused<<<Bn, NT, 0, stream>>>(ego, lane, score, out, slots);
}